// Round 1
// 325.950 us; speedup vs baseline: 1.0593x; 1.0593x over previous
//
#include <hip/hip_runtime.h>
#include <stdint.h>

#define NCOMP 5
#define DM 1024
#define LN_EPS 1e-5f

typedef __attribute__((ext_vector_type(8))) __bf16 bf16x8;
typedef __attribute__((ext_vector_type(4))) float f32x4;

__device__ __forceinline__ unsigned short f2bf(float f) {
    unsigned u = __builtin_bit_cast(unsigned, f);
    u += 0x7fffu + ((u >> 16) & 1u);   // round-to-nearest-even
    return (unsigned short)(u >> 16);
}

// -------- kernel 1: fused compartment LayerNorm + (W+I)->bf16 --------
// block = 128 threads, 4 units per block. unit < M: token LN; else: W row.
__global__ __launch_bounds__(128) void ln_w_kernel(
    const float* __restrict__ x, const int* __restrict__ cid,
    const float* __restrict__ gamma, const float* __restrict__ beta,
    const float* __restrict__ scale, const float* __restrict__ W,
    unsigned short* __restrict__ y, unsigned short* __restrict__ Wb, int M)
{
    const int tid = threadIdx.x;
    __shared__ float red[8];
    const int base = blockIdx.x * 4;
#pragma unroll
    for (int u = 0; u < 4; u++) {
        const int t = base + u;                 // block-uniform
        if (t < M) {
            const float* xp = x + (size_t)t * DM + tid * 8;
            const float4 a = *(const float4*)xp;
            const float4 b = *(const float4*)(xp + 4);
            float s  = a.x + a.y + a.z + a.w + b.x + b.y + b.z + b.w;
            float ss = a.x*a.x + a.y*a.y + a.z*a.z + a.w*a.w
                     + b.x*b.x + b.y*b.y + b.z*b.z + b.w*b.w;
#pragma unroll
            for (int off = 32; off > 0; off >>= 1) {
                s  += __shfl_down(s, off);
                ss += __shfl_down(ss, off);
            }
            float* rr = red + (u & 1) * 4;      // parity slot: no WAR hazard
            if ((tid & 63) == 0) { rr[tid >> 6] = s; rr[2 + (tid >> 6)] = ss; }
            __syncthreads();
            const float mu  = (rr[0] + rr[1]) * (1.0f / DM);
            const float var = (rr[2] + rr[3]) * (1.0f / DM) - mu * mu;
            const float rs  = rsqrtf(var + LN_EPS);
            const int craw  = cid[t];
            const bool valid = craw < NCOMP;    // reference guard
            const int c = min(max(craw, 0), NCOMP - 1);
            const float sc = scale[c];
            const float* gp = gamma + c * DM + tid * 8;
            const float* bp = beta  + c * DM + tid * 8;
            const float4 g0 = *(const float4*)gp;
            const float4 g1 = *(const float4*)(gp + 4);
            const float4 b0 = *(const float4*)bp;
            const float4 b1 = *(const float4*)(bp + 4);
            float o[8];
            o[0] = valid ? ((a.x - mu) * rs * g0.x + b0.x) * sc : a.x;
            o[1] = valid ? ((a.y - mu) * rs * g0.y + b0.y) * sc : a.y;
            o[2] = valid ? ((a.z - mu) * rs * g0.z + b0.z) * sc : a.z;
            o[3] = valid ? ((a.w - mu) * rs * g0.w + b0.w) * sc : a.w;
            o[4] = valid ? ((b.x - mu) * rs * g1.x + b1.x) * sc : b.x;
            o[5] = valid ? ((b.y - mu) * rs * g1.y + b1.y) * sc : b.y;
            o[6] = valid ? ((b.z - mu) * rs * g1.z + b1.z) * sc : b.z;
            o[7] = valid ? ((b.w - mu) * rs * g1.w + b1.w) * sc : b.w;
            uint4 p;
            p.x = (unsigned)f2bf(o[0]) | ((unsigned)f2bf(o[1]) << 16);
            p.y = (unsigned)f2bf(o[2]) | ((unsigned)f2bf(o[3]) << 16);
            p.z = (unsigned)f2bf(o[4]) | ((unsigned)f2bf(o[5]) << 16);
            p.w = (unsigned)f2bf(o[6]) | ((unsigned)f2bf(o[7]) << 16);
            *(uint4*)(y + (size_t)t * DM + tid * 8) = p;
        } else {
            const int row = t - M;              // 0..DM-1
            const float* wp = W + (size_t)row * DM + tid * 8;
            const float4 a = *(const float4*)wp;
            const float4 b = *(const float4*)(wp + 4);
            float o[8] = {a.x, a.y, a.z, a.w, b.x, b.y, b.z, b.w};
            const int d = row - tid * 8;        // fold identity: out = y*(W+I)^T + b
            if (d >= 0 && d < 8) o[d] += 1.0f;
            uint4 p;
            p.x = (unsigned)f2bf(o[0]) | ((unsigned)f2bf(o[1]) << 16);
            p.y = (unsigned)f2bf(o[2]) | ((unsigned)f2bf(o[3]) << 16);
            p.z = (unsigned)f2bf(o[4]) | ((unsigned)f2bf(o[5]) << 16);
            p.w = (unsigned)f2bf(o[6]) | ((unsigned)f2bf(o[7]) << 16);
            *(uint4*)(Wb + (size_t)row * DM + tid * 8) = p;
        }
    }
}

// -------- kernel 2: C = A * Bp^T + bias (Bp = W + I, bf16) --------
// 256x256 tile, BK=32, quad-buffered LDS (128 KiB), 8 waves (2Mx4N),
// per-wave output 128x64. Phase-pipelined: stage tile t+3 while computing
// tile t; counted vmcnt(8) once per K-tile (never 0 in steady state);
// raw s_barrier (NO __syncthreads -> no vmcnt(0) drain in the loop).
__device__ __forceinline__ void gld16(const unsigned short* g, unsigned short* l) {
    __builtin_amdgcn_global_load_lds(
        (const __attribute__((address_space(1))) unsigned int*)(uintptr_t)g,
        (__attribute__((address_space(3))) unsigned int*)(uintptr_t)l,
        16, 0, 0);
}

__global__ __launch_bounds__(512, 2) void gemm_kernel(
    const unsigned short* __restrict__ A,
    const unsigned short* __restrict__ Bp,
    const float* __restrict__ bias,
    float* __restrict__ C, int M)
{
    constexpr int K = 1024, N = 1024;
    constexpr int BUF = 16384;                    // shorts per buffer: A 8192 + B 8192
    __shared__ __align__(16) unsigned short smem[4 * BUF];   // 128 KiB

    const int tid  = threadIdx.x;
    const int lane = tid & 63;
    const int wave = tid >> 6;
    const int wm   = (wave >> 2) * 128;           // 2 M-wave-groups
    const int wn   = (wave & 3) * 64;             // 4 N-wave-groups

    // T1: XCD-aware block swizzle (nwg = 512, divisible by 8 -> bijective)
    const int nwg = gridDim.x;
    int wg = blockIdx.x;
    if ((nwg & 7) == 0) wg = (wg & 7) * (nwg >> 3) + (wg >> 3);
    const int bm = (wg >> 2) * 256;               // n fastest -> A-panel L2 reuse
    const int bn = (wg & 3) * 256;

    // ---- staging addressing (T2: linear LDS dest + pre-swizzled global src) ----
    // physical chunk p holds logical chunk p ^ ((row>>1)&3); rows are 16-aligned
    // per wave-load so the XOR key reduces to lane bits.
    const int qsrc = (((lane & 3) ^ ((lane >> 3) & 3))) * 8;  // element offset
    const int rA0  = (wave * 2) * 16 + (lane >> 2);
    const unsigned short* gA0 = A  + (size_t)(bm + rA0) * K + qsrc;
    const unsigned short* gA1 = A  + (size_t)(bm + rA0 + 16) * K + qsrc;
    const unsigned short* gB0 = Bp + (size_t)(bn + rA0) * K + qsrc;
    const unsigned short* gB1 = Bp + (size_t)(bn + rA0 + 16) * K + qsrc;
    const int sA0 = (wave * 2) * 512 + lane * 8;  // shorts within buf (linear)
    const int sA1 = sA0 + 512;
    const int sB0 = 8192 + sA0;
    const int sB1 = 8192 + sA1;

    // ---- fragment read offset (swizzled): 2-way max bank aliasing = free ----
    const int fr   = lane & 15;
    const int quad = lane >> 4;
    const int loff = fr * 32 + ((quad ^ ((fr >> 1) & 3)) * 8);

    f32x4 acc[8][4] = {};

    // prologue: stage K-tiles 0,1,2 (3 tiles = 12 loads/thread in flight)
#pragma unroll
    for (int kt = 0; kt < 3; ++kt) {
        unsigned short* sb = smem + kt * BUF;
        gld16(gA0 + kt * 32, sb + sA0);
        gld16(gA1 + kt * 32, sb + sA1);
        gld16(gB0 + kt * 32, sb + sB0);
        gld16(gB1 + kt * 32, sb + sB1);
    }
    gA0 += 96; gA1 += 96; gB0 += 96; gB1 += 96;   // -> tile 3

    asm volatile("s_waitcnt vmcnt(8)" ::: "memory");  // tile 0 landed
    __builtin_amdgcn_s_barrier();

    for (int t = 0; t < 32; ++t) {
        const unsigned short* Asb = smem + (t & 3) * BUF;
        const unsigned short* Bsb = Asb + 8192;
        unsigned short* stg = smem + ((t + 3) & 3) * BUF;  // == buf of tile t-1
        const bool do_stage = (t < 29);

        // ---- phase A: mh=0 ----
        bf16x8 bfr[4], af[4];
#pragma unroll
        for (int j = 0; j < 4; ++j)
            bfr[j] = *(const bf16x8*)&Bsb[(wn + j * 16) * 32 + loff];
#pragma unroll
        for (int j = 0; j < 4; ++j)
            af[j] = *(const bf16x8*)&Asb[(wm + j * 16) * 32 + loff];
        if (do_stage) {                            // stage A-half of tile t+3
            gld16(gA0, stg + sA0);
            gld16(gA1, stg + sA1);
        }
        __builtin_amdgcn_s_barrier();
        asm volatile("s_waitcnt lgkmcnt(0)" ::: "memory");
        __builtin_amdgcn_s_setprio(1);
#pragma unroll
        for (int j = 0; j < 4; ++j)
#pragma unroll
            for (int n = 0; n < 4; ++n)
                acc[j][n] = __builtin_amdgcn_mfma_f32_16x16x32_bf16(
                    af[j], bfr[n], acc[j][n], 0, 0, 0);
        __builtin_amdgcn_s_setprio(0);
        __builtin_amdgcn_s_barrier();

        // ---- phase B: mh=1 (bfr reused from registers) ----
#pragma unroll
        for (int j = 0; j < 4; ++j)
            af[j] = *(const bf16x8*)&Asb[(wm + 64 + j * 16) * 32 + loff];
        if (do_stage) {                            // stage B-half of tile t+3
            gld16(gB0, stg + sB0);
            gld16(gB1, stg + sB1);
            gA0 += 32; gA1 += 32; gB0 += 32; gB1 += 32;
        }
        // once-per-K-tile counted wait: tile t+1 fully landed, tiles t+2,t+3
        // (8 loads) may stay in flight. Tail drains 8 -> 4 -> 0.
        if (t < 29)       asm volatile("s_waitcnt vmcnt(8)" ::: "memory");
        else if (t == 29) asm volatile("s_waitcnt vmcnt(4)" ::: "memory");
        else              asm volatile("s_waitcnt vmcnt(0)" ::: "memory");
        __builtin_amdgcn_s_barrier();
        asm volatile("s_waitcnt lgkmcnt(0)" ::: "memory");
        __builtin_amdgcn_s_setprio(1);
#pragma unroll
        for (int j = 0; j < 4; ++j)
#pragma unroll
            for (int n = 0; n < 4; ++n)
                acc[4 + j][n] = __builtin_amdgcn_mfma_f32_16x16x32_bf16(
                    af[j], bfr[n], acc[4 + j][n], 0, 0, 0);
        __builtin_amdgcn_s_setprio(0);
        __builtin_amdgcn_s_barrier();
    }

    // ---- epilogue: out = acc + bias, per-wave LDS transpose (no barriers) ----
    // C/D layout: col = fr, row = quad*4 + reg. Padded stride 68 breaks conflicts.
    float* tb = (float*)smem + wave * 1088;   // 16 rows x 68 floats, per-wave private
    const int erow = lane >> 3;               // 0..7
    const int ecol = (lane & 7) * 4;          // 0..28
    const float4 bv0 = *(const float4*)&bias[bn + wn + ecol];
    const float4 bv1 = *(const float4*)&bias[bn + wn + 32 + ecol];
#pragma unroll
    for (int mi = 0; mi < 8; ++mi) {
#pragma unroll
        for (int ni = 0; ni < 4; ++ni)
#pragma unroll
            for (int r = 0; r < 4; ++r)
                tb[(quad * 4 + r) * 68 + ni * 16 + fr] = acc[mi][ni][r];
        // same-wave LDS: in-order pipe + compiler lgkmcnt waits; no barrier
#pragma unroll
        for (int j = 0; j < 4; ++j) {
            const int row  = (j >> 1) * 8 + erow;        // 0..15
            const int colg = (j & 1) * 32 + ecol;        // 0..60
            const int gr = bm + wm + mi * 16 + row;
            const float4 v = *(const float4*)&tb[row * 68 + colg];
            const float4 bv = (j & 1) ? bv1 : bv0;
            float4 o;
            o.x = v.x + bv.x; o.y = v.y + bv.y;
            o.z = v.z + bv.z; o.w = v.w + bv.w;
            *(float4*)&C[(size_t)gr * N + bn + wn + colg] = o;  // full 128B lines
        }
    }
}

extern "C" void kernel_launch(void* const* d_in, const int* in_sizes, int n_in,
                              void* d_out, int out_size, void* d_ws, size_t ws_size,
                              hipStream_t stream)
{
    const float* x     = (const float*)d_in[0];
    const int*   cid   = (const int*)d_in[1];
    const float* gamma = (const float*)d_in[2];
    const float* beta  = (const float*)d_in[3];
    const float* scale = (const float*)d_in[4];
    const float* W     = (const float*)d_in[5];
    const float* bias  = (const float*)d_in[6];
    float* out = (float*)d_out;

    const int M = in_sizes[0] / DM;                        // 32768 tokens
    unsigned short* yb = (unsigned short*)d_ws;            // M*1024 bf16 = 64 MB
    unsigned short* Wb = yb + (size_t)M * DM;              // 1024*1024 bf16 = 2 MB

    ln_w_kernel<<<(M + DM) / 4, 128, 0, stream>>>(x, cid, gamma, beta, scale, W, yb, Wb, M);
    gemm_kernel<<<dim3((M / 256) * 4), 512, 0, stream>>>(yb, Wb, bias, out, M);
}